// Round 8
// baseline (677.146 us; speedup 1.0000x reference)
//
#include <hip/hip_runtime.h>

#define NB 4
#define NM 80
#define NT 65536
#define NL 20

// ---------- types ----------
typedef __bf16 bf16x8 __attribute__((ext_vector_type(8), may_alias));
typedef float f32x4 __attribute__((ext_vector_type(4), may_alias));
typedef unsigned int u32x2 __attribute__((ext_vector_type(2), may_alias));
typedef unsigned int u32x4 __attribute__((ext_vector_type(4), may_alias));

// ---------- d_ws layout (ushort units) ----------
// [0, 491520): 60 phase-blocks (pg = l*3 + {0=D,1=S,2=R}) of 8192 ushorts.
//   chunk c = plane*8 + m*2 + ks (plane 0=hi,1=lo), lane lam, j in [0,8):
//   W[plane][m*16 + (lam&15)][ks*32 + (lam>>4)*8 + j] at c*512 + lam*8 + j.
//   LDS-staged linearly: each lane's bf16x8 fragment at chunk*1024 + lane*16 B.
#define WCHI 491520
#define WCLO 497664
#define W1HI 503808
#define W1LO 507904

__device__ __forceinline__ unsigned f2u(float x) { return __float_as_uint(x); }
__device__ __forceinline__ float u2f(unsigned u) { return __uint_as_float(u); }
__device__ __forceinline__ unsigned pack2(float a, float b) {
    return (f2u(a) >> 16) | (f2u(b) & 0xffff0000u);
}
// round-to-nearest-even bf16 of a, in the HIGH 16 bits
__device__ __forceinline__ unsigned rne_hi(float a) {
    unsigned u = f2u(a);
    return (u + 0x7fffu + ((u >> 16) & 1u)) & 0xffff0000u;
}
// RNE pack (single-plane bf16 values: f, s — rounding mode matters here)
__device__ __forceinline__ unsigned pack2_rne(float a, float b) {
    return (rne_hi(a) >> 16) | rne_hi(b);
}
// hw packed f32->2xbf16 (mode-agnostic uses only: hi/lo split planes)
__device__ __forceinline__ unsigned cvtpk(float a, float b) {
    unsigned r;
    asm("v_cvt_pk_bf16_f32 %0, %1, %2" : "=v"(r) : "v"(a), "v"(b));
    return r;
}
__device__ __forceinline__ float fast_tanh(float v) {
    float e = __expf(2.0f * v);
    return 1.0f - 2.0f / (e + 1.0f);
}
__device__ __forceinline__ f32x4 mm3(bf16x8 ah, bf16x8 al, bf16x8 bh, bf16x8 bl, f32x4 c) {
    c = __builtin_amdgcn_mfma_f32_16x16x32_bf16(ah, bh, c, 0, 0, 0);
    c = __builtin_amdgcn_mfma_f32_16x16x32_bf16(ah, bl, c, 0, 0, 0);
    c = __builtin_amdgcn_mfma_f32_16x16x32_bf16(al, bh, c, 0, 0, 0);
    return c;
}
__device__ __forceinline__ f32x4 mm2(bf16x8 ah, bf16x8 al, bf16x8 b, f32x4 c) {
    c = __builtin_amdgcn_mfma_f32_16x16x32_bf16(ah, b, c, 0, 0, 0);
    c = __builtin_amdgcn_mfma_f32_16x16x32_bf16(al, b, c, 0, 0, 0);
    return c;
}
// split 4 fp32 (D-reg order) into packed (hi,lo) bf16 dword pairs.
// hi rounding mode irrelevant: lo exactly captures the residual.
__device__ __forceinline__ void split_pack(f32x4 v, u32x2& hi, u32x2& lo) {
    hi[0] = cvtpk(v[0], v[1]);
    hi[1] = cvtpk(v[2], v[3]);
    float r0 = v[0] - u2f(hi[0] << 16);
    float r1 = v[1] - u2f(hi[0] & 0xffff0000u);
    float r2 = v[2] - u2f(hi[1] << 16);
    float r3 = v[3] - u2f(hi[1] & 0xffff0000u);
    lo[0] = cvtpk(r0, r1);
    lo[1] = cvtpk(r2, r3);
}
__device__ __forceinline__ unsigned shf(unsigned v, int sl) {
    return (unsigned)__shfl((int)v, sl, 64);
}
// Build MFMA B-fragment (one K=32 chunk) from packed D-layout dwords.
__device__ __forceinline__ u32x4 gatherB(u32x2 p0, u32x2 p1, int slA, int slB, bool hiSel) {
    unsigned a0 = shf(p0[0], slA), b0 = shf(p1[0], slA);
    unsigned a1 = shf(p0[1], slA), b1 = shf(p1[1], slA);
    unsigned a2 = shf(p0[0], slB), b2 = shf(p1[0], slB);
    unsigned a3 = shf(p0[1], slB), b3 = shf(p1[1], slB);
    u32x4 r;
    r[0] = hiSel ? b0 : a0;
    r[1] = hiSel ? b1 : a1;
    r[2] = hiSel ? b2 : a2;
    r[3] = hiSel ? b3 : a3;
    return r;
}
__device__ __forceinline__ bf16x8 asbf(const u32x4& v) { return *(const bf16x8*)&v; }

// stage one 16 KB phase-block quarter (4 chunks) via async global->LDS
__device__ __forceinline__ void stage_phase(const unsigned short* __restrict__ wsu,
                                            unsigned short* lbase, int pg, int wave, int lane) {
#pragma unroll
    for (int jj = 0; jj < 4; ++jj) {
        const unsigned short* g = wsu + (size_t)pg * 8192 + (wave * 4 + jj) * 512 + lane * 8;
        unsigned short* lp = lbase + (wave * 4 + jj) * 512;
        __builtin_amdgcn_global_load_lds(
            (const __attribute__((address_space(1))) unsigned int*)g,
            (__attribute__((address_space(3))) unsigned int*)lp, 16, 0, 0);
    }
}

#define PHASE_SYNC() do { \
    asm volatile("s_waitcnt vmcnt(0)" ::: "memory"); \
    __builtin_amdgcn_s_barrier(); \
} while (0)

// ---------- prep: split weights into bf16 hi/lo, phase-chunked layout ----------
extern "C" __global__ void __launch_bounds__(256)
wavenet_prep(const float* __restrict__ wc, const float* __restrict__ wd,
             const float* __restrict__ wsk, const float* __restrict__ wr,
             const float* __restrict__ w1, unsigned short* __restrict__ o)
{
    int i = blockIdx.x * 256 + threadIdx.x;
    if (i < 491520) {
        int pg = i >> 13;                 // phase-block
        int within = i & 8191;
        int c = within >> 9;              // chunk
        int lam = (within >> 3) & 63;     // lane
        int j = i & 7;
        int plane = c >> 3, m = (c >> 1) & 3, ks = c & 1;
        int row = m * 16 + (lam & 15);
        int k = ks * 32 + (lam >> 4) * 8 + j;
        int l = pg / 3, p = pg - 3 * l;
        const float* W = (p == 0) ? wd : (p == 1) ? wsk : wr;
        float v = W[(l * 64 + row) * 64 + k];
        unsigned uh = f2u(v) & 0xffff0000u;
        unsigned val = plane ? (f2u(v - u2f(uh)) >> 16) : (uh >> 16);
        o[i] = (unsigned short)val;
    } else if (i < 497664) {              // wc: [64][80] -> padded [64][96]
        int idx = i - 491520;
        int r = idx / 96, mm = idx - r * 96;
        float v = (mm < NM) ? wc[r * NM + mm] : 0.0f;
        unsigned uh = f2u(v) & 0xffff0000u;
        o[WCHI + idx] = (unsigned short)(uh >> 16);
        o[WCLO + idx] = (unsigned short)(f2u(v - u2f(uh)) >> 16);
    } else if (i < 501760) {              // w1: [64][64]
        int idx = i - 497664;
        float v = w1[idx];
        unsigned uh = f2u(v) & 0xffff0000u;
        o[W1HI + idx] = (unsigned short)(uh >> 16);
        o[W1LO + idx] = (unsigned short)(f2u(v - u2f(uh)) >> 16);
    }
}

// ---------- main kernel: 16 cols/wave, 4-wave WG, pipelined weight LDS ----------
extern "C" __global__ void __launch_bounds__(256)
__attribute__((amdgpu_waves_per_eu(3, 4)))
wavenet_mfma(const float* __restrict__ x, const float* __restrict__ bc,
             const float* __restrict__ bd, const float* __restrict__ br,
             const float* __restrict__ bs, const float* __restrict__ b1,
             const float* __restrict__ w2, const float* __restrict__ b2,
             const unsigned short* __restrict__ wsu, float* __restrict__ out)
{
    __shared__ __align__(16) unsigned short wbuf[2][8192];   // 2 x 16 KB ping-pong

    const int tid = threadIdx.x;
    const int wave = tid >> 6;
    const int lane = tid & 63;
    const int q = lane >> 4;
    const int c16 = lane & 15;
    const int wcol0 = wave * 16;              // this wave's 16 columns

    const int slA = ((lane & 16) << 1) + c16;  // 32*(q&1) + c16
    const int slB = slA + 16;
    const bool hiSel = lane >= 32;

    const int gcol0 = blockIdx.x * 64;
    const int bidx = gcol0 >> 16;              // T = 65536
    const float* xbase = x + (size_t)bidx * NM * NT + (gcol0 & (NT - 1));

    // prologue: stage phase 0 weights (lands under conv compute)
    stage_phase(wsu, &wbuf[0][0], 0, wave, lane);

    // persistent per-lane state (MFMA C/D layout)
    f32x4 h[4];
    f32x4 skipacc[4];
#pragma unroll
    for (int m = 0; m < 4; ++m) skipacc[m] = (f32x4){0.f, 0.f, 0.f, 0.f};

    // ================= causal conv: h = Wc @ x + bc  (K=96, zero-padded) =================
    {
        const int colL = wcol0 + c16;
        const float* xcp = xbase + colL;

        bf16x8 Bh[3], Bl[3];
#pragma unroll
        for (int ks = 0; ks < 3; ++ks) {
            u32x4 ph, pl;
#pragma unroll
            for (int w = 0; w < 4; ++w) {
                const int m0 = ks * 32 + q * 8 + 2 * w;
                float a, bv;
                if (ks < 2) {
                    a  = xcp[(size_t)m0 * NT];
                    bv = xcp[(size_t)(m0 + 1) * NT];
                } else {
                    const int ma = (m0 < NM) ? m0 : 0;
                    const int mb = (m0 + 1 < NM) ? (m0 + 1) : 0;
                    a  = (m0 < NM) ? xcp[(size_t)ma * NT] : 0.0f;
                    bv = (m0 + 1 < NM) ? xcp[(size_t)mb * NT] : 0.0f;
                }
                const float la = a - u2f(f2u(a) & 0xffff0000u);
                const float lb = bv - u2f(f2u(bv) & 0xffff0000u);
                ph[w] = pack2(a, bv);
                pl[w] = pack2(la, lb);
            }
            Bh[ks] = asbf(ph);
            Bl[ks] = asbf(pl);
        }

#pragma unroll
        for (int m = 0; m < 4; ++m) {
            f32x4 acc = *(const f32x4*)(bc + m * 16 + q * 4);
#pragma unroll
            for (int ks = 0; ks < 3; ++ks) {
                bf16x8 Ah = *(const bf16x8*)(wsu + WCHI + (m * 16 + c16) * 96 + ks * 32 + q * 8);
                bf16x8 Al = *(const bf16x8*)(wsu + WCLO + (m * 16 + c16) * 96 + ks * 32 + q * 8);
                acc = mm3(Ah, Al, Bh[ks], Bl[ks], acc);
            }
            h[m] = acc;
        }
    }

    // ================= 20 residual layers, pipelined weight staging =================
    int buf = 0;
#pragma unroll 1
    for (int l = 0; l < NL; ++l) {
        const float* bdl = bd + l * 64;
        const float* brl = br + l * 64;

        // ===== phase D: f = tanh(Wd h + bd) =====
        PHASE_SYNC();                                   // wd(l) staged & visible
        stage_phase(wsu, &wbuf[buf ^ 1][0], 3 * l + 1, wave, lane);   // prefetch ws(l)
        {
            const unsigned short* wb = &wbuf[buf][0];

            // build B-fragments of h via shuffle (hi+lo planes)
            u32x4 BhH[2], BlH[2];
            {
                u32x2 Ph[4], Pl[4];
#pragma unroll
                for (int m = 0; m < 4; ++m) split_pack(h[m], Ph[m], Pl[m]);
#pragma unroll
                for (int ks = 0; ks < 2; ++ks) {
                    BhH[ks] = gatherB(Ph[ks * 2], Ph[ks * 2 + 1], slA, slB, hiSel);
                    BlH[ks] = gatherB(Pl[ks * 2], Pl[ks * 2 + 1], slA, slB, hiSel);
                }
            }

            u32x2 Pf[4];   // packed f, D-layout
#pragma unroll
            for (int m = 0; m < 4; ++m) {
                bf16x8 Ah[2], Al[2];
#pragma unroll
                for (int ks = 0; ks < 2; ++ks) {
                    Ah[ks] = *(const bf16x8*)(wb + (m * 2 + ks) * 512 + lane * 8);
                    Al[ks] = *(const bf16x8*)(wb + (8 + m * 2 + ks) * 512 + lane * 8);
                }
                f32x4 acc = *(const f32x4*)(bdl + m * 16 + q * 4);
#pragma unroll
                for (int ks = 0; ks < 2; ++ks)
                    acc = mm3(Ah[ks], Al[ks], asbf(BhH[ks]), asbf(BlH[ks]), acc);
                Pf[m][0] = pack2_rne(fast_tanh(acc[0]), fast_tanh(acc[1]));
                Pf[m][1] = pack2_rne(fast_tanh(acc[2]), fast_tanh(acc[3]));
            }
            buf ^= 1;

            // B-fragments of f via shuffle (single plane)
            u32x4 BF[2];
#pragma unroll
            for (int ks = 0; ks < 2; ++ks)
                BF[ks] = gatherB(Pf[ks * 2], Pf[ks * 2 + 1], slA, slB, hiSel);

            // ===== phase S: skip += Ws f =====
            PHASE_SYNC();                               // ws(l) staged & visible
            stage_phase(wsu, &wbuf[buf ^ 1][0], 3 * l + 2, wave, lane);   // prefetch wr(l)
            wb = &wbuf[buf][0];
#pragma unroll
            for (int m = 0; m < 4; ++m) {
                bf16x8 Ah[2], Al[2];
#pragma unroll
                for (int ks = 0; ks < 2; ++ks) {
                    Ah[ks] = *(const bf16x8*)(wb + (m * 2 + ks) * 512 + lane * 8);
                    Al[ks] = *(const bf16x8*)(wb + (8 + m * 2 + ks) * 512 + lane * 8);
                }
#pragma unroll
                for (int ks = 0; ks < 2; ++ks)
                    skipacc[m] = mm2(Ah[ks], Al[ks], asbf(BF[ks]), skipacc[m]);
            }
            buf ^= 1;

            // ===== phase R: h = h + Wr f + br =====
            PHASE_SYNC();                               // wr(l) staged & visible
            if (l < NL - 1)
                stage_phase(wsu, &wbuf[buf ^ 1][0], 3 * l + 3, wave, lane);  // prefetch wd(l+1)
            wb = &wbuf[buf][0];
#pragma unroll
            for (int m = 0; m < 4; ++m) {
                bf16x8 Ah[2], Al[2];
#pragma unroll
                for (int ks = 0; ks < 2; ++ks) {
                    Ah[ks] = *(const bf16x8*)(wb + (m * 2 + ks) * 512 + lane * 8);
                    Al[ks] = *(const bf16x8*)(wb + (8 + m * 2 + ks) * 512 + lane * 8);
                }
                f32x4 br4 = *(const f32x4*)(brl + m * 16 + q * 4);
                f32x4 c = h[m];
#pragma unroll
                for (int i = 0; i < 4; ++i) c[i] += br4[i];
#pragma unroll
                for (int ks = 0; ks < 2; ++ks)
                    c = mm2(Ah[ks], Al[ks], asbf(BF[ks]), c);
                h[m] = c;
            }
            buf ^= 1;
        }
    }

    // ================= post-net =================
    u32x2 Ps[4];
#pragma unroll
    for (int m = 0; m < 4; ++m) {
        f32x4 bsum = (f32x4){0.f, 0.f, 0.f, 0.f};
#pragma unroll
        for (int l = 0; l < NL; ++l) {
            f32x4 bv = *(const f32x4*)(bs + l * 64 + m * 16 + q * 4);
#pragma unroll
            for (int i = 0; i < 4; ++i) bsum[i] += bv[i];
        }
        Ps[m][0] = pack2_rne(fast_tanh(skipacc[m][0] + bsum[0]),
                             fast_tanh(skipacc[m][1] + bsum[1]));
        Ps[m][1] = pack2_rne(fast_tanh(skipacc[m][2] + bsum[2]),
                             fast_tanh(skipacc[m][3] + bsum[3]));
    }
    u32x4 BS[2];
#pragma unroll
    for (int ks = 0; ks < 2; ++ks)
        BS[ks] = gatherB(Ps[ks * 2], Ps[ks * 2 + 1], slA, slB, hiSel);

    f32x4 s2a[4];
#pragma unroll
    for (int m = 0; m < 4; ++m) {
        bf16x8 Ah[2], Al[2];
#pragma unroll
        for (int ks = 0; ks < 2; ++ks) {
            Ah[ks] = *(const bf16x8*)(wsu + W1HI + (m * 16 + c16) * 64 + ks * 32 + q * 8);
            Al[ks] = *(const bf16x8*)(wsu + W1LO + (m * 16 + c16) * 64 + ks * 32 + q * 8);
        }
        f32x4 acc = *(const f32x4*)(b1 + m * 16 + q * 4);
#pragma unroll
        for (int ks = 0; ks < 2; ++ks)
            acc = mm2(Ah[ks], Al[ks], asbf(BS[ks]), acc);
#pragma unroll
        for (int i = 0; i < 4; ++i) s2a[m][i] = fast_tanh(acc[i]);
    }

    f32x4 w24[4];
#pragma unroll
    for (int m = 0; m < 4; ++m) w24[m] = *(const f32x4*)(w2 + m * 16 + q * 4);
    const float b2v = b2[0];
    float p = 0.0f;
#pragma unroll
    for (int m = 0; m < 4; ++m)
#pragma unroll
        for (int i = 0; i < 4; ++i)
            p = fmaf(w24[m][i], s2a[m][i], p);
    p += __shfl_xor(p, 16);
    p += __shfl_xor(p, 32);
    if (q == 0)
        out[gcol0 + wcol0 + c16] = b2v + p;
}

extern "C" void kernel_launch(void* const* d_in, const int* in_sizes, int n_in,
                              void* d_out, int out_size, void* d_ws, size_t ws_size,
                              hipStream_t stream) {
    const float* x  = (const float*)d_in[0];
    const float* wc = (const float*)d_in[1];
    const float* bc = (const float*)d_in[2];
    const float* wd = (const float*)d_in[3];
    const float* bd = (const float*)d_in[4];
    const float* wr = (const float*)d_in[5];
    const float* br = (const float*)d_in[6];
    const float* ws = (const float*)d_in[7];
    const float* bs = (const float*)d_in[8];
    const float* w1 = (const float*)d_in[9];
    const float* b1 = (const float*)d_in[10];
    const float* w2 = (const float*)d_in[11];
    const float* b2 = (const float*)d_in[12];
    float* out = (float*)d_out;
    unsigned short* wsu = (unsigned short*)d_ws;

    hipLaunchKernelGGL(wavenet_prep, dim3(1960), dim3(256), 0, stream,
                       wc, wd, ws, wr, w1, wsu);
    hipLaunchKernelGGL(wavenet_mfma, dim3((NB * NT) / 64), dim3(256), 0, stream,
                       x, bc, bd, br, bs, b1, w2, b2, wsu, out);
}

// Round 9
// 593.884 us; speedup vs baseline: 1.1402x; 1.1402x over previous
//
#include <hip/hip_runtime.h>

#define NB 4
#define NM 80
#define NT 65536
#define NL 20

// ---------- types ----------
typedef __bf16 bf16x8 __attribute__((ext_vector_type(8), may_alias));
typedef float f32x4 __attribute__((ext_vector_type(4), may_alias));
typedef unsigned int u32x2 __attribute__((ext_vector_type(2), may_alias));
typedef unsigned int u32x4 __attribute__((ext_vector_type(4), may_alias));

// ---------- d_ws layout (ushort units) ----------
// [0, 491520): 60 phase-blocks (pg = l*3 + {0=D,1=S,2=R}) of 8192 ushorts.
//   chunk c = plane*8 + m*2 + ks (plane 0=hi RNE, 1=lo trunc-of-residual),
//   lane lam, j in [0,8): W[plane][m*16+(lam&15)][ks*32+(lam>>4)*8+j]
//   at c*512 + lam*8 + j.  LDS-staged linearly: lane's bf16x8 fragment at
//   chunk*1024 + lane*16 bytes (conflict-free ds_read_b128).
#define WCHI 491520
#define WCLO 497664
#define W1HI 503808
#define W1LO 507904

__device__ __forceinline__ unsigned f2u(float x) { return __float_as_uint(x); }
__device__ __forceinline__ float u2f(unsigned u) { return __uint_as_float(u); }
__device__ __forceinline__ unsigned pack2(float a, float b) {
    return (f2u(a) >> 16) | (f2u(b) & 0xffff0000u);
}
// round-to-nearest-even bf16 of a, in the HIGH 16 bits
__device__ __forceinline__ unsigned rne_hi(float a) {
    unsigned u = f2u(a);
    return (u + 0x7fffu + ((u >> 16) & 1u)) & 0xffff0000u;
}
__device__ __forceinline__ unsigned pack2_rne(float a, float b) {
    return (rne_hi(a) >> 16) | rne_hi(b);
}
// hw packed f32->2xbf16 (mode-agnostic uses only: hi/lo split planes)
__device__ __forceinline__ unsigned cvtpk(float a, float b) {
    unsigned r;
    asm("v_cvt_pk_bf16_f32 %0, %1, %2" : "=v"(r) : "v"(a), "v"(b));
    return r;
}
__device__ __forceinline__ float fast_tanh(float v) {
    float e = __expf(2.0f * v);
    return 1.0f - 2.0f / (e + 1.0f);
}
__device__ __forceinline__ f32x4 mm3(bf16x8 ah, bf16x8 al, bf16x8 bh, bf16x8 bl, f32x4 c) {
    c = __builtin_amdgcn_mfma_f32_16x16x32_bf16(ah, bh, c, 0, 0, 0);
    c = __builtin_amdgcn_mfma_f32_16x16x32_bf16(ah, bl, c, 0, 0, 0);
    c = __builtin_amdgcn_mfma_f32_16x16x32_bf16(al, bh, c, 0, 0, 0);
    return c;
}
__device__ __forceinline__ f32x4 mm2(bf16x8 ah, bf16x8 al, bf16x8 b, f32x4 c) {
    c = __builtin_amdgcn_mfma_f32_16x16x32_bf16(ah, b, c, 0, 0, 0);
    c = __builtin_amdgcn_mfma_f32_16x16x32_bf16(al, b, c, 0, 0, 0);
    return c;
}
// split 4 fp32 (D-reg order) into packed (hi,lo) bf16 dword pairs.
// hi rounding mode irrelevant: lo exactly captures the residual.
__device__ __forceinline__ void split_pack(f32x4 v, u32x2& hi, u32x2& lo) {
    hi[0] = cvtpk(v[0], v[1]);
    hi[1] = cvtpk(v[2], v[3]);
    float r0 = v[0] - u2f(hi[0] << 16);
    float r1 = v[1] - u2f(hi[0] & 0xffff0000u);
    float r2 = v[2] - u2f(hi[1] << 16);
    float r3 = v[3] - u2f(hi[1] & 0xffff0000u);
    lo[0] = cvtpk(r0, r1);
    lo[1] = cvtpk(r2, r3);
}
__device__ __forceinline__ unsigned shf(unsigned v, int sl) {
    return (unsigned)__shfl((int)v, sl, 64);
}
// Build MFMA B-fragment (one K=32 chunk) from packed D-layout dwords.
__device__ __forceinline__ u32x4 gatherB(u32x2 p0, u32x2 p1, int slA, int slB, bool hiSel) {
    unsigned a0 = shf(p0[0], slA), b0 = shf(p1[0], slA);
    unsigned a1 = shf(p0[1], slA), b1 = shf(p1[1], slA);
    unsigned a2 = shf(p0[0], slB), b2 = shf(p1[0], slB);
    unsigned a3 = shf(p0[1], slB), b3 = shf(p1[1], slB);
    u32x4 r;
    r[0] = hiSel ? b0 : a0;
    r[1] = hiSel ? b1 : a1;
    r[2] = hiSel ? b2 : a2;
    r[3] = hiSel ? b3 : a3;
    return r;
}
__device__ __forceinline__ bf16x8 asbf(const u32x4& v) { return *(const bf16x8*)&v; }

// stage NCH chunks/wave of a phase-block via async global->LDS
template <int NCH>
__device__ __forceinline__ void stage_phase(const unsigned short* __restrict__ wsu,
                                            unsigned short* lbase, int pg, int wave, int lane) {
#pragma unroll
    for (int jj = 0; jj < NCH; ++jj) {
        const unsigned short* g = wsu + (size_t)pg * 8192 + (wave * NCH + jj) * 512 + lane * 8;
        unsigned short* lp = lbase + (wave * NCH + jj) * 512;
        __builtin_amdgcn_global_load_lds(
            (const __attribute__((address_space(1))) unsigned int*)g,
            (__attribute__((address_space(3))) unsigned int*)lp, 16, 0, 0);
    }
}

#define PHASE_SYNC() do { \
    asm volatile("s_waitcnt vmcnt(0)" ::: "memory"); \
    __builtin_amdgcn_s_barrier(); \
} while (0)

// ---------- prep: split weights into bf16 hi(RNE)/lo planes, phase-chunked ----------
extern "C" __global__ void __launch_bounds__(256)
wavenet_prep(const float* __restrict__ wc, const float* __restrict__ wd,
             const float* __restrict__ wsk, const float* __restrict__ wr,
             const float* __restrict__ w1, unsigned short* __restrict__ o)
{
    int i = blockIdx.x * 256 + threadIdx.x;
    if (i < 491520) {
        int pg = i >> 13;                 // phase-block
        int within = i & 8191;
        int c = within >> 9;              // chunk
        int lam = (within >> 3) & 63;     // lane
        int j = i & 7;
        int plane = c >> 3, m = (c >> 1) & 3, ks = c & 1;
        int row = m * 16 + (lam & 15);
        int k = ks * 32 + (lam >> 4) * 8 + j;
        int l = pg / 3, p = pg - 3 * l;
        const float* W = (p == 0) ? wd : (p == 1) ? wsk : wr;
        float v = W[(l * 64 + row) * 64 + k];
        unsigned uh = rne_hi(v);          // RNE hi (lo compensates exactly where used)
        unsigned val = plane ? (f2u(v - u2f(uh)) >> 16) : (uh >> 16);
        o[i] = (unsigned short)val;
    } else if (i < 497664) {              // wc: [64][80] -> padded [64][96]
        int idx = i - 491520;
        int r = idx / 96, mm = idx - r * 96;
        float v = (mm < NM) ? wc[r * NM + mm] : 0.0f;
        unsigned uh = rne_hi(v);
        o[WCHI + idx] = (unsigned short)(uh >> 16);
        o[WCLO + idx] = (unsigned short)(f2u(v - u2f(uh)) >> 16);
    } else if (i < 501760) {              // w1: [64][64]
        int idx = i - 497664;
        float v = w1[idx];
        unsigned uh = rne_hi(v);
        o[W1HI + idx] = (unsigned short)(uh >> 16);
        o[W1LO + idx] = (unsigned short)(f2u(v - u2f(uh)) >> 16);
    }
}

// ---------- main kernel: 32 cols/wave, 4-wave WG, forced 4 waves/EU ----------
extern "C" __global__ void __launch_bounds__(256, 4)
wavenet_mfma(const float* __restrict__ x, const float* __restrict__ bc,
             const float* __restrict__ bd, const float* __restrict__ br,
             const float* __restrict__ bs, const float* __restrict__ b1,
             const float* __restrict__ w2, const float* __restrict__ b2,
             const unsigned short* __restrict__ wsu, float* __restrict__ out)
{
    __shared__ __align__(16) unsigned short wbuf[2][8192];   // 2 x 16 KB ping-pong

    const int tid = threadIdx.x;
    const int wave = tid >> 6;
    const int lane = tid & 63;
    const int q = lane >> 4;
    const int c16 = lane & 15;
    const int wcol0 = wave * 32;

    const int slA = ((lane & 16) << 1) + c16;  // 32*(q&1) + c16
    const int slB = slA + 16;
    const bool hiSel = lane >= 32;

    const int gcol0 = blockIdx.x * 128;
    const int bidx = gcol0 >> 16;              // T = 65536
    const float* xbase = x + (size_t)bidx * NM * NT + (gcol0 & (NT - 1));

    // prologue: stage phase 0 weights (lands under conv compute)
    stage_phase<4>(wsu, &wbuf[0][0], 0, wave, lane);

    // persistent per-lane state (MFMA C/D layout)
    f32x4 h[4][2];
    f32x4 skipacc[4][2];
#pragma unroll
    for (int m = 0; m < 4; ++m)
#pragma unroll
        for (int nt = 0; nt < 2; ++nt)
            skipacc[m][nt] = (f32x4){0.f, 0.f, 0.f, 0.f};

    // ================= causal conv: h = Wc @ x + bc  (K=96, zero-padded) =================
#pragma unroll
    for (int nt = 0; nt < 2; ++nt) {
        const int colL = wcol0 + nt * 16 + c16;
        const float* xcp = xbase + colL;

        bf16x8 Bh[3], Bl[3];
#pragma unroll
        for (int ks = 0; ks < 3; ++ks) {
            u32x4 ph, pl;
#pragma unroll
            for (int w = 0; w < 4; ++w) {
                const int m0 = ks * 32 + q * 8 + 2 * w;
                float a, bv;
                if (ks < 2) {
                    a  = xcp[(size_t)m0 * NT];
                    bv = xcp[(size_t)(m0 + 1) * NT];
                } else {
                    const int ma = (m0 < NM) ? m0 : 0;
                    const int mb = (m0 + 1 < NM) ? (m0 + 1) : 0;
                    a  = (m0 < NM) ? xcp[(size_t)ma * NT] : 0.0f;
                    bv = (m0 + 1 < NM) ? xcp[(size_t)mb * NT] : 0.0f;
                }
                const float la = a - u2f(f2u(a) & 0xffff0000u);
                const float lb = bv - u2f(f2u(bv) & 0xffff0000u);
                ph[w] = pack2(a, bv);
                pl[w] = pack2(la, lb);
            }
            Bh[ks] = asbf(ph);
            Bl[ks] = asbf(pl);
        }

#pragma unroll
        for (int m = 0; m < 4; ++m) {
            f32x4 acc = *(const f32x4*)(bc + m * 16 + q * 4);
#pragma unroll
            for (int ks = 0; ks < 3; ++ks) {
                bf16x8 Ah = *(const bf16x8*)(wsu + WCHI + (m * 16 + c16) * 96 + ks * 32 + q * 8);
                bf16x8 Al = *(const bf16x8*)(wsu + WCLO + (m * 16 + c16) * 96 + ks * 32 + q * 8);
                acc = mm3(Ah, Al, Bh[ks], Bl[ks], acc);
            }
            h[m][nt] = acc;
        }
    }

    // ================= 20 residual layers, pipelined weight staging =================
    int buf = 0;
#pragma unroll 1
    for (int l = 0; l < NL; ++l) {
        const float* bdl = bd + l * 64;
        const float* brl = br + l * 64;

        // ===== phase D: f = tanh(Wd h + bd) =====
        PHASE_SYNC();                                   // wd(l) staged & visible
        stage_phase<2>(wsu, &wbuf[buf ^ 1][0], 3 * l + 1, wave, lane);   // prefetch ws(l) hi
        {
            const unsigned short* wb = &wbuf[buf][0];

            // build B-fragments of h via shuffle (hi+lo planes)
            u32x4 BhH[2][2], BlH[2][2];
#pragma unroll
            for (int nt = 0; nt < 2; ++nt) {
                u32x2 Ph[4], Pl[4];
#pragma unroll
                for (int m = 0; m < 4; ++m) split_pack(h[m][nt], Ph[m], Pl[m]);
#pragma unroll
                for (int ks = 0; ks < 2; ++ks) {
                    BhH[nt][ks] = gatherB(Ph[ks * 2], Ph[ks * 2 + 1], slA, slB, hiSel);
                    BlH[nt][ks] = gatherB(Pl[ks * 2], Pl[ks * 2 + 1], slA, slB, hiSel);
                }
            }

            u32x2 Pf[2][4];   // packed f, D-layout
#pragma unroll
            for (int m = 0; m < 4; ++m) {
                bf16x8 Ah[2], Al[2];
#pragma unroll
                for (int ks = 0; ks < 2; ++ks) {
                    Ah[ks] = *(const bf16x8*)(wb + (m * 2 + ks) * 512 + lane * 8);
                    Al[ks] = *(const bf16x8*)(wb + (8 + m * 2 + ks) * 512 + lane * 8);
                }
                f32x4 bd4 = *(const f32x4*)(bdl + m * 16 + q * 4);
#pragma unroll
                for (int nt = 0; nt < 2; ++nt) {
                    f32x4 acc = bd4;
#pragma unroll
                    for (int ks = 0; ks < 2; ++ks)
                        acc = mm3(Ah[ks], Al[ks], asbf(BhH[nt][ks]), asbf(BlH[nt][ks]), acc);
                    Pf[nt][m][0] = pack2_rne(fast_tanh(acc[0]), fast_tanh(acc[1]));
                    Pf[nt][m][1] = pack2_rne(fast_tanh(acc[2]), fast_tanh(acc[3]));
                }
            }
            buf ^= 1;

            // B-fragments of f via shuffle (single plane)
            u32x4 BF[2][2];
#pragma unroll
            for (int nt = 0; nt < 2; ++nt)
#pragma unroll
                for (int ks = 0; ks < 2; ++ks)
                    BF[nt][ks] = gatherB(Pf[nt][ks * 2], Pf[nt][ks * 2 + 1], slA, slB, hiSel);

            // ===== phase S: skip += Ws f  (hi-plane only, RNE weights) =====
            PHASE_SYNC();                               // ws(l) hi staged & visible
            stage_phase<4>(wsu, &wbuf[buf ^ 1][0], 3 * l + 2, wave, lane);   // prefetch wr(l)
            wb = &wbuf[buf][0];
#pragma unroll
            for (int m = 0; m < 4; ++m) {
                bf16x8 Ah[2];
#pragma unroll
                for (int ks = 0; ks < 2; ++ks)
                    Ah[ks] = *(const bf16x8*)(wb + (m * 2 + ks) * 512 + lane * 8);
#pragma unroll
                for (int nt = 0; nt < 2; ++nt)
#pragma unroll
                    for (int ks = 0; ks < 2; ++ks)
                        skipacc[m][nt] = __builtin_amdgcn_mfma_f32_16x16x32_bf16(
                            Ah[ks], asbf(BF[nt][ks]), skipacc[m][nt], 0, 0, 0);
            }
            buf ^= 1;

            // ===== phase R: h = h + Wr f + br =====
            PHASE_SYNC();                               // wr(l) staged & visible
            if (l < NL - 1)
                stage_phase<4>(wsu, &wbuf[buf ^ 1][0], 3 * l + 3, wave, lane);  // prefetch wd(l+1)
            wb = &wbuf[buf][0];
#pragma unroll
            for (int m = 0; m < 4; ++m) {
                bf16x8 Ah[2], Al[2];
#pragma unroll
                for (int ks = 0; ks < 2; ++ks) {
                    Ah[ks] = *(const bf16x8*)(wb + (m * 2 + ks) * 512 + lane * 8);
                    Al[ks] = *(const bf16x8*)(wb + (8 + m * 2 + ks) * 512 + lane * 8);
                }
                f32x4 br4 = *(const f32x4*)(brl + m * 16 + q * 4);
#pragma unroll
                for (int nt = 0; nt < 2; ++nt) {
                    f32x4 c = h[m][nt];
#pragma unroll
                    for (int i = 0; i < 4; ++i) c[i] += br4[i];
#pragma unroll
                    for (int ks = 0; ks < 2; ++ks)
                        c = mm2(Ah[ks], Al[ks], asbf(BF[nt][ks]), c);
                    h[m][nt] = c;
                }
            }
            buf ^= 1;
        }
    }

    // ================= post-net =================
    u32x2 Ps[2][4];
#pragma unroll
    for (int m = 0; m < 4; ++m) {
        f32x4 bsum = (f32x4){0.f, 0.f, 0.f, 0.f};
#pragma unroll
        for (int l = 0; l < NL; ++l) {
            f32x4 bv = *(const f32x4*)(bs + l * 64 + m * 16 + q * 4);
#pragma unroll
            for (int i = 0; i < 4; ++i) bsum[i] += bv[i];
        }
#pragma unroll
        for (int nt = 0; nt < 2; ++nt) {
            Ps[nt][m][0] = pack2_rne(fast_tanh(skipacc[m][nt][0] + bsum[0]),
                                     fast_tanh(skipacc[m][nt][1] + bsum[1]));
            Ps[nt][m][1] = pack2_rne(fast_tanh(skipacc[m][nt][2] + bsum[2]),
                                     fast_tanh(skipacc[m][nt][3] + bsum[3]));
        }
    }
    u32x4 BS[2][2];
#pragma unroll
    for (int nt = 0; nt < 2; ++nt)
#pragma unroll
        for (int ks = 0; ks < 2; ++ks)
            BS[nt][ks] = gatherB(Ps[nt][ks * 2], Ps[nt][ks * 2 + 1], slA, slB, hiSel);

    f32x4 s2a[4][2];
#pragma unroll
    for (int m = 0; m < 4; ++m) {
        bf16x8 Ah[2], Al[2];
#pragma unroll
        for (int ks = 0; ks < 2; ++ks) {
            Ah[ks] = *(const bf16x8*)(wsu + W1HI + (m * 16 + c16) * 64 + ks * 32 + q * 8);
            Al[ks] = *(const bf16x8*)(wsu + W1LO + (m * 16 + c16) * 64 + ks * 32 + q * 8);
        }
        f32x4 b14 = *(const f32x4*)(b1 + m * 16 + q * 4);
#pragma unroll
        for (int nt = 0; nt < 2; ++nt) {
            f32x4 acc = b14;
#pragma unroll
            for (int ks = 0; ks < 2; ++ks)
                acc = mm2(Ah[ks], Al[ks], asbf(BS[nt][ks]), acc);
#pragma unroll
            for (int i = 0; i < 4; ++i) s2a[m][nt][i] = fast_tanh(acc[i]);
        }
    }

    f32x4 w24[4];
#pragma unroll
    for (int m = 0; m < 4; ++m) w24[m] = *(const f32x4*)(w2 + m * 16 + q * 4);
    const float b2v = b2[0];
#pragma unroll
    for (int nt = 0; nt < 2; ++nt) {
        float p = 0.0f;
#pragma unroll
        for (int m = 0; m < 4; ++m)
#pragma unroll
            for (int i = 0; i < 4; ++i)
                p = fmaf(w24[m][i], s2a[m][nt][i], p);
        p += __shfl_xor(p, 16);
        p += __shfl_xor(p, 32);
        if (q == 0)
            out[gcol0 + wcol0 + nt * 16 + c16] = b2v + p;
    }
}

extern "C" void kernel_launch(void* const* d_in, const int* in_sizes, int n_in,
                              void* d_out, int out_size, void* d_ws, size_t ws_size,
                              hipStream_t stream) {
    const float* x  = (const float*)d_in[0];
    const float* wc = (const float*)d_in[1];
    const float* bc = (const float*)d_in[2];
    const float* wd = (const float*)d_in[3];
    const float* bd = (const float*)d_in[4];
    const float* wr = (const float*)d_in[5];
    const float* br = (const float*)d_in[6];
    const float* ws = (const float*)d_in[7];
    const float* bs = (const float*)d_in[8];
    const float* w1 = (const float*)d_in[9];
    const float* b1 = (const float*)d_in[10];
    const float* w2 = (const float*)d_in[11];
    const float* b2 = (const float*)d_in[12];
    float* out = (float*)d_out;
    unsigned short* wsu = (unsigned short*)d_ws;

    hipLaunchKernelGGL(wavenet_prep, dim3(1960), dim3(256), 0, stream,
                       wc, wd, ws, wr, w1, wsu);
    hipLaunchKernelGGL(wavenet_mfma, dim3((NB * NT) / 128), dim3(256), 0, stream,
                       x, bc, bd, br, bs, b1, w2, b2, wsu, out);
}

// Round 11
// 571.150 us; speedup vs baseline: 1.1856x; 1.0398x over previous
//
#include <hip/hip_runtime.h>

#define NB 4
#define NM 80
#define NT 65536
#define NL 20

// ---------- types ----------
typedef __bf16 bf16x8 __attribute__((ext_vector_type(8), may_alias));
typedef float f32x4 __attribute__((ext_vector_type(4), may_alias));
typedef unsigned int u32x2 __attribute__((ext_vector_type(2), may_alias));
typedef unsigned int u32x4 __attribute__((ext_vector_type(4), may_alias));

// ---------- d_ws layout (ushort units) ----------
// [0, 491520): 60 phase-blocks (pg = l*3 + {0=D,1=S,2=R}) of 8192 ushorts.
//   chunk c = plane*8 + m*2 + ks (plane 0=hi RNE, 1=lo trunc-of-residual),
//   lane lam, j in [0,8): W[plane][m*16+(lam&15)][ks*32+(lam>>4)*8+j]
//   at c*512 + lam*8 + j.  LDS-staged linearly: lane's bf16x8 fragment at
//   chunk*1024 + lane*16 bytes (conflict-free ds_read_b128).
#define WCHI 491520
#define WCLO 497664
#define W1HI 503808
#define W1LO 507904

__device__ __forceinline__ unsigned f2u(float x) { return __float_as_uint(x); }
__device__ __forceinline__ float u2f(unsigned u) { return __uint_as_float(u); }
__device__ __forceinline__ unsigned pack2(float a, float b) {
    return (f2u(a) >> 16) | (f2u(b) & 0xffff0000u);
}
// round-to-nearest-even bf16 of a, in the HIGH 16 bits
__device__ __forceinline__ unsigned rne_hi(float a) {
    unsigned u = f2u(a);
    return (u + 0x7fffu + ((u >> 16) & 1u)) & 0xffff0000u;
}
__device__ __forceinline__ unsigned pack2_rne(float a, float b) {
    return (rne_hi(a) >> 16) | rne_hi(b);
}
// hw packed f32->2xbf16 (mode-agnostic uses only: hi/lo split planes)
__device__ __forceinline__ unsigned cvtpk(float a, float b) {
    unsigned r;
    asm("v_cvt_pk_bf16_f32 %0, %1, %2" : "=v"(r) : "v"(a), "v"(b));
    return r;
}
__device__ __forceinline__ float fast_tanh(float v) {
    float e = __expf(2.0f * v);
    return 1.0f - 2.0f / (e + 1.0f);
}
__device__ __forceinline__ f32x4 mm3(bf16x8 ah, bf16x8 al, bf16x8 bh, bf16x8 bl, f32x4 c) {
    c = __builtin_amdgcn_mfma_f32_16x16x32_bf16(ah, bh, c, 0, 0, 0);
    c = __builtin_amdgcn_mfma_f32_16x16x32_bf16(ah, bl, c, 0, 0, 0);
    c = __builtin_amdgcn_mfma_f32_16x16x32_bf16(al, bh, c, 0, 0, 0);
    return c;
}
__device__ __forceinline__ f32x4 mm2(bf16x8 ah, bf16x8 al, bf16x8 b, f32x4 c) {
    c = __builtin_amdgcn_mfma_f32_16x16x32_bf16(ah, b, c, 0, 0, 0);
    c = __builtin_amdgcn_mfma_f32_16x16x32_bf16(al, b, c, 0, 0, 0);
    return c;
}
// split 4 fp32 (D-reg order) into packed (hi,lo) bf16 dword pairs.
// hi rounding mode irrelevant: lo exactly captures the residual.
__device__ __forceinline__ void split_pack(f32x4 v, u32x2& hi, u32x2& lo) {
    hi[0] = cvtpk(v[0], v[1]);
    hi[1] = cvtpk(v[2], v[3]);
    float r0 = v[0] - u2f(hi[0] << 16);
    float r1 = v[1] - u2f(hi[0] & 0xffff0000u);
    float r2 = v[2] - u2f(hi[1] << 16);
    float r3 = v[3] - u2f(hi[1] & 0xffff0000u);
    lo[0] = cvtpk(r0, r1);
    lo[1] = cvtpk(r2, r3);
}
__device__ __forceinline__ unsigned shf(unsigned v, int sl) {
    return (unsigned)__shfl((int)v, sl, 64);
}
// Build MFMA B-fragment (one K=32 chunk) from packed D-layout dwords.
__device__ __forceinline__ u32x4 gatherB(u32x2 p0, u32x2 p1, int slA, int slB, bool hiSel) {
    unsigned a0 = shf(p0[0], slA), b0 = shf(p1[0], slA);
    unsigned a1 = shf(p0[1], slA), b1 = shf(p1[1], slA);
    unsigned a2 = shf(p0[0], slB), b2 = shf(p1[0], slB);
    unsigned a3 = shf(p0[1], slB), b3 = shf(p1[1], slB);
    u32x4 r;
    r[0] = hiSel ? b0 : a0;
    r[1] = hiSel ? b1 : a1;
    r[2] = hiSel ? b2 : a2;
    r[3] = hiSel ? b3 : a3;
    return r;
}
__device__ __forceinline__ bf16x8 asbf(const u32x4& v) { return *(const bf16x8*)&v; }

// stage NCH chunks/wave of a phase-block via async global->LDS
template <int NCH>
__device__ __forceinline__ void stage_phase(const unsigned short* __restrict__ wsu,
                                            unsigned short* lbase, int pg, int wave, int lane) {
#pragma unroll
    for (int jj = 0; jj < NCH; ++jj) {
        const unsigned short* g = wsu + (size_t)pg * 8192 + (wave * NCH + jj) * 512 + lane * 8;
        unsigned short* lp = lbase + (wave * NCH + jj) * 512;
        __builtin_amdgcn_global_load_lds(
            (const __attribute__((address_space(1))) unsigned int*)g,
            (__attribute__((address_space(3))) unsigned int*)lp, 16, 0, 0);
    }
}

// Full fence + barrier. Drains vmcnt(0) AND lgkmcnt(0) before s_barrier, and is
// a compiler-level ordering point — fixes the r10 race where a wave crossed the
// barrier with ds_reads of the ping-pong buffer still in flight while other
// waves' global_load_lds overwrote it (lgkmcnt was never drained by the old
// inline-asm sync; reg-only MFMA consumers can sink below asm per rule #18).
// Pipelining is preserved: the stage for phase p+1 is issued AFTER this sync
// and only drained at sync p+1, so it stays in flight under phase p's compute.
#define PHASE_SYNC() __syncthreads()

// ---------- prep: split weights into bf16 hi(RNE)/lo planes, phase-chunked ----------
extern "C" __global__ void __launch_bounds__(256)
wavenet_prep(const float* __restrict__ wc, const float* __restrict__ wd,
             const float* __restrict__ wsk, const float* __restrict__ wr,
             const float* __restrict__ w1, unsigned short* __restrict__ o)
{
    int i = blockIdx.x * 256 + threadIdx.x;
    if (i < 491520) {
        int pg = i >> 13;                 // phase-block
        int within = i & 8191;
        int c = within >> 9;              // chunk
        int lam = (within >> 3) & 63;     // lane
        int j = i & 7;
        int plane = c >> 3, m = (c >> 1) & 3, ks = c & 1;
        int row = m * 16 + (lam & 15);
        int k = ks * 32 + (lam >> 4) * 8 + j;
        int l = pg / 3, p = pg - 3 * l;
        const float* W = (p == 0) ? wd : (p == 1) ? wsk : wr;
        float v = W[(l * 64 + row) * 64 + k];
        unsigned uh = rne_hi(v);          // RNE hi (lo compensates exactly where used)
        unsigned val = plane ? (f2u(v - u2f(uh)) >> 16) : (uh >> 16);
        o[i] = (unsigned short)val;
    } else if (i < 497664) {              // wc: [64][80] -> padded [64][96]
        int idx = i - 491520;
        int r = idx / 96, mm = idx - r * 96;
        float v = (mm < NM) ? wc[r * NM + mm] : 0.0f;
        unsigned uh = rne_hi(v);
        o[WCHI + idx] = (unsigned short)(uh >> 16);
        o[WCLO + idx] = (unsigned short)(f2u(v - u2f(uh)) >> 16);
    } else if (i < 501760) {              // w1: [64][64]
        int idx = i - 497664;
        float v = w1[idx];
        unsigned uh = rne_hi(v);
        o[W1HI + idx] = (unsigned short)(uh >> 16);
        o[W1LO + idx] = (unsigned short)(f2u(v - u2f(uh)) >> 16);
    }
}

// ---------- main kernel: 32 cols/wave, 4-wave WG, 3 waves/EU (no spill) ----------
extern "C" __global__ void __launch_bounds__(256, 3)
wavenet_mfma(const float* __restrict__ x, const float* __restrict__ bc,
             const float* __restrict__ bd, const float* __restrict__ br,
             const float* __restrict__ bs, const float* __restrict__ b1,
             const float* __restrict__ w2, const float* __restrict__ b2,
             const unsigned short* __restrict__ wsu, float* __restrict__ out)
{
    __shared__ __align__(16) unsigned short wbuf[2][8192];   // 2 x 16 KB ping-pong

    const int tid = threadIdx.x;
    const int wave = tid >> 6;
    const int lane = tid & 63;
    const int q = lane >> 4;
    const int c16 = lane & 15;
    const int wcol0 = wave * 32;

    const int slA = ((lane & 16) << 1) + c16;  // 32*(q&1) + c16
    const int slB = slA + 16;
    const bool hiSel = lane >= 32;

    const int gcol0 = blockIdx.x * 128;
    const int bidx = gcol0 >> 16;              // T = 65536
    const float* xbase = x + (size_t)bidx * NM * NT + (gcol0 & (NT - 1));

    // prologue: stage phase 0 weights (lands under conv compute)
    stage_phase<4>(wsu, &wbuf[0][0], 0, wave, lane);

    // persistent per-lane state (MFMA C/D layout)
    f32x4 h[4][2];
    f32x4 skipacc[4][2];
#pragma unroll
    for (int m = 0; m < 4; ++m)
#pragma unroll
        for (int nt = 0; nt < 2; ++nt)
            skipacc[m][nt] = (f32x4){0.f, 0.f, 0.f, 0.f};

    // ================= causal conv: h = Wc @ x + bc  (K=96, zero-padded) =================
#pragma unroll
    for (int nt = 0; nt < 2; ++nt) {
        const int colL = wcol0 + nt * 16 + c16;
        const float* xcp = xbase + colL;

        bf16x8 Bh[3], Bl[3];
#pragma unroll
        for (int ks = 0; ks < 3; ++ks) {
            u32x4 ph, pl;
#pragma unroll
            for (int w = 0; w < 4; ++w) {
                const int m0 = ks * 32 + q * 8 + 2 * w;
                float a, bv;
                if (ks < 2) {
                    a  = xcp[(size_t)m0 * NT];
                    bv = xcp[(size_t)(m0 + 1) * NT];
                } else {
                    const int ma = (m0 < NM) ? m0 : 0;
                    const int mb = (m0 + 1 < NM) ? (m0 + 1) : 0;
                    a  = (m0 < NM) ? xcp[(size_t)ma * NT] : 0.0f;
                    bv = (m0 + 1 < NM) ? xcp[(size_t)mb * NT] : 0.0f;
                }
                const float la = a - u2f(f2u(a) & 0xffff0000u);
                const float lb = bv - u2f(f2u(bv) & 0xffff0000u);
                ph[w] = pack2(a, bv);
                pl[w] = pack2(la, lb);
            }
            Bh[ks] = asbf(ph);
            Bl[ks] = asbf(pl);
        }

#pragma unroll
        for (int m = 0; m < 4; ++m) {
            f32x4 acc = *(const f32x4*)(bc + m * 16 + q * 4);
#pragma unroll
            for (int ks = 0; ks < 3; ++ks) {
                bf16x8 Ah = *(const bf16x8*)(wsu + WCHI + (m * 16 + c16) * 96 + ks * 32 + q * 8);
                bf16x8 Al = *(const bf16x8*)(wsu + WCLO + (m * 16 + c16) * 96 + ks * 32 + q * 8);
                acc = mm3(Ah, Al, Bh[ks], Bl[ks], acc);
            }
            h[m][nt] = acc;
        }
    }

    // ================= 20 residual layers, pipelined weight staging =================
    int buf = 0;
#pragma unroll 1
    for (int l = 0; l < NL; ++l) {
        const float* bdl = bd + l * 64;
        const float* brl = br + l * 64;

        // ===== phase D: f = tanh(Wd h + bd) =====
        PHASE_SYNC();                                   // wd(l) staged & visible
        stage_phase<2>(wsu, &wbuf[buf ^ 1][0], 3 * l + 1, wave, lane);   // prefetch ws(l) hi
        {
            const unsigned short* wb = &wbuf[buf][0];

            // build B-fragments of h via shuffle (hi+lo planes)
            u32x4 BhH[2][2], BlH[2][2];
#pragma unroll
            for (int nt = 0; nt < 2; ++nt) {
                u32x2 Ph[4], Pl[4];
#pragma unroll
                for (int m = 0; m < 4; ++m) split_pack(h[m][nt], Ph[m], Pl[m]);
#pragma unroll
                for (int ks = 0; ks < 2; ++ks) {
                    BhH[nt][ks] = gatherB(Ph[ks * 2], Ph[ks * 2 + 1], slA, slB, hiSel);
                    BlH[nt][ks] = gatherB(Pl[ks * 2], Pl[ks * 2 + 1], slA, slB, hiSel);
                }
            }

            u32x2 Pf[2][4];   // packed f, D-layout
#pragma unroll
            for (int m = 0; m < 4; ++m) {
                bf16x8 Ah[2], Al[2];
#pragma unroll
                for (int ks = 0; ks < 2; ++ks) {
                    Ah[ks] = *(const bf16x8*)(wb + (m * 2 + ks) * 512 + lane * 8);
                    Al[ks] = *(const bf16x8*)(wb + (8 + m * 2 + ks) * 512 + lane * 8);
                }
                f32x4 bd4 = *(const f32x4*)(bdl + m * 16 + q * 4);
#pragma unroll
                for (int nt = 0; nt < 2; ++nt) {
                    f32x4 acc = bd4;
#pragma unroll
                    for (int ks = 0; ks < 2; ++ks)
                        acc = mm3(Ah[ks], Al[ks], asbf(BhH[nt][ks]), asbf(BlH[nt][ks]), acc);
                    Pf[nt][m][0] = pack2_rne(fast_tanh(acc[0]), fast_tanh(acc[1]));
                    Pf[nt][m][1] = pack2_rne(fast_tanh(acc[2]), fast_tanh(acc[3]));
                }
            }
            buf ^= 1;

            // B-fragments of f via shuffle (single plane)
            u32x4 BF[2][2];
#pragma unroll
            for (int nt = 0; nt < 2; ++nt)
#pragma unroll
                for (int ks = 0; ks < 2; ++ks)
                    BF[nt][ks] = gatherB(Pf[nt][ks * 2], Pf[nt][ks * 2 + 1], slA, slB, hiSel);

            // ===== phase S: skip += Ws f  (hi-plane only, RNE weights) =====
            PHASE_SYNC();                               // ws(l) hi staged & visible
            stage_phase<4>(wsu, &wbuf[buf ^ 1][0], 3 * l + 2, wave, lane);   // prefetch wr(l)
            wb = &wbuf[buf][0];
#pragma unroll
            for (int m = 0; m < 4; ++m) {
                bf16x8 Ah[2];
#pragma unroll
                for (int ks = 0; ks < 2; ++ks)
                    Ah[ks] = *(const bf16x8*)(wb + (m * 2 + ks) * 512 + lane * 8);
#pragma unroll
                for (int nt = 0; nt < 2; ++nt)
#pragma unroll
                    for (int ks = 0; ks < 2; ++ks)
                        skipacc[m][nt] = __builtin_amdgcn_mfma_f32_16x16x32_bf16(
                            Ah[ks], asbf(BF[nt][ks]), skipacc[m][nt], 0, 0, 0);
            }
            buf ^= 1;

            // ===== phase R: h = h + Wr f + br =====
            PHASE_SYNC();                               // wr(l) staged & visible
            if (l < NL - 1)
                stage_phase<4>(wsu, &wbuf[buf ^ 1][0], 3 * l + 3, wave, lane);  // prefetch wd(l+1)
            wb = &wbuf[buf][0];
#pragma unroll
            for (int m = 0; m < 4; ++m) {
                bf16x8 Ah[2], Al[2];
#pragma unroll
                for (int ks = 0; ks < 2; ++ks) {
                    Ah[ks] = *(const bf16x8*)(wb + (m * 2 + ks) * 512 + lane * 8);
                    Al[ks] = *(const bf16x8*)(wb + (8 + m * 2 + ks) * 512 + lane * 8);
                }
                f32x4 br4 = *(const f32x4*)(brl + m * 16 + q * 4);
#pragma unroll
                for (int nt = 0; nt < 2; ++nt) {
                    f32x4 c = h[m][nt];
#pragma unroll
                    for (int i = 0; i < 4; ++i) c[i] += br4[i];
#pragma unroll
                    for (int ks = 0; ks < 2; ++ks)
                        c = mm2(Ah[ks], Al[ks], asbf(BF[nt][ks]), c);
                    h[m][nt] = c;
                }
            }
            buf ^= 1;
        }
    }

    // ================= post-net =================
    u32x2 Ps[2][4];
#pragma unroll
    for (int m = 0; m < 4; ++m) {
        f32x4 bsum = (f32x4){0.f, 0.f, 0.f, 0.f};
#pragma unroll
        for (int l = 0; l < NL; ++l) {
            f32x4 bv = *(const f32x4*)(bs + l * 64 + m * 16 + q * 4);
#pragma unroll
            for (int i = 0; i < 4; ++i) bsum[i] += bv[i];
        }
#pragma unroll
        for (int nt = 0; nt < 2; ++nt) {
            Ps[nt][m][0] = pack2_rne(fast_tanh(skipacc[m][nt][0] + bsum[0]),
                                     fast_tanh(skipacc[m][nt][1] + bsum[1]));
            Ps[nt][m][1] = pack2_rne(fast_tanh(skipacc[m][nt][2] + bsum[2]),
                                     fast_tanh(skipacc[m][nt][3] + bsum[3]));
        }
    }
    u32x4 BS[2][2];
#pragma unroll
    for (int nt = 0; nt < 2; ++nt)
#pragma unroll
        for (int ks = 0; ks < 2; ++ks)
            BS[nt][ks] = gatherB(Ps[nt][ks * 2], Ps[nt][ks * 2 + 1], slA, slB, hiSel);

    f32x4 s2a[4][2];
#pragma unroll
    for (int m = 0; m < 4; ++m) {
        bf16x8 Ah[2], Al[2];
#pragma unroll
        for (int ks = 0; ks < 2; ++ks) {
            Ah[ks] = *(const bf16x8*)(wsu + W1HI + (m * 16 + c16) * 64 + ks * 32 + q * 8);
            Al[ks] = *(const bf16x8*)(wsu + W1LO + (m * 16 + c16) * 64 + ks * 32 + q * 8);
        }
        f32x4 b14 = *(const f32x4*)(b1 + m * 16 + q * 4);
#pragma unroll
        for (int nt = 0; nt < 2; ++nt) {
            f32x4 acc = b14;
#pragma unroll
            for (int ks = 0; ks < 2; ++ks)
                acc = mm2(Ah[ks], Al[ks], asbf(BS[nt][ks]), acc);
#pragma unroll
            for (int i = 0; i < 4; ++i) s2a[m][nt][i] = fast_tanh(acc[i]);
        }
    }

    f32x4 w24[4];
#pragma unroll
    for (int m = 0; m < 4; ++m) w24[m] = *(const f32x4*)(w2 + m * 16 + q * 4);
    const float b2v = b2[0];
#pragma unroll
    for (int nt = 0; nt < 2; ++nt) {
        float p = 0.0f;
#pragma unroll
        for (int m = 0; m < 4; ++m)
#pragma unroll
            for (int i = 0; i < 4; ++i)
                p = fmaf(w24[m][i], s2a[m][nt][i], p);
        p += __shfl_xor(p, 16);
        p += __shfl_xor(p, 32);
        if (q == 0)
            out[gcol0 + wcol0 + nt * 16 + c16] = b2v + p;
    }
}

extern "C" void kernel_launch(void* const* d_in, const int* in_sizes, int n_in,
                              void* d_out, int out_size, void* d_ws, size_t ws_size,
                              hipStream_t stream) {
    const float* x  = (const float*)d_in[0];
    const float* wc = (const float*)d_in[1];
    const float* bc = (const float*)d_in[2];
    const float* wd = (const float*)d_in[3];
    const float* bd = (const float*)d_in[4];
    const float* wr = (const float*)d_in[5];
    const float* br = (const float*)d_in[6];
    const float* ws = (const float*)d_in[7];
    const float* bs = (const float*)d_in[8];
    const float* w1 = (const float*)d_in[9];
    const float* b1 = (const float*)d_in[10];
    const float* w2 = (const float*)d_in[11];
    const float* b2 = (const float*)d_in[12];
    float* out = (float*)d_out;
    unsigned short* wsu = (unsigned short*)d_ws;

    hipLaunchKernelGGL(wavenet_prep, dim3(1960), dim3(256), 0, stream,
                       wc, wd, ws, wr, w1, wsu);
    hipLaunchKernelGGL(wavenet_mfma, dim3((NB * NT) / 128), dim3(256), 0, stream,
                       x, bc, bd, br, bs, b1, w2, b2, wsu, out);
}